// Round 2
// baseline (903.372 us; speedup 1.0000x reference)
//
#include <hip/hip_runtime.h>
#include <math.h>

#define B_ 16
#define S_ 6
#define E_ 256
#define NH_ 8
#define HD_ 32
#define HW_ 4096            // 64*64
#define ROWS_ (B_*S_*E_)    // 24576
#define SE_ (S_*E_)         // 1536
#define BS_ (B_*S_)         // 96
#define CROSS_N_ ((size_t)ROWS_*HW_)  // 100663296

// ---------------- Kernel 1: spatial mean + temporal pos ----------------
// one block (256 thr) per (b,s,e) row of 4096 contiguous floats
__global__ __launch_bounds__(256) void pool_kernel(
    const float* __restrict__ ff, const float* __restrict__ tpos,
    float* __restrict__ g)
{
    const int row = blockIdx.x;                    // b*1536 + s*256 + e
    const float4* p = (const float4*)(ff + (size_t)row * HW_);
    float sum = 0.f;
    #pragma unroll
    for (int i = 0; i < 4; ++i) {
        float4 v = p[threadIdx.x + i * 256];
        sum += v.x + v.y + v.z + v.w;
    }
    #pragma unroll
    for (int off = 32; off > 0; off >>= 1)
        sum += __shfl_down(sum, off, 64);
    __shared__ float part[4];
    if ((threadIdx.x & 63) == 0) part[threadIdx.x >> 6] = sum;
    __syncthreads();
    if (threadIdx.x == 0) {
        float tot = part[0] + part[1] + part[2] + part[3];
        g[row] = tot * (1.0f / HW_) + tpos[row % SE_];
    }
}

// ---------------- Kernel 2a: QKV projection ----------------
// one block per (b,s); wave-per-row matvec, coalesced float4 W loads
__global__ __launch_bounds__(256) void qkv_kernel(
    const float* __restrict__ g,
    const float* __restrict__ Wq, const float* __restrict__ bq,
    const float* __restrict__ Wk, const float* __restrict__ bk,
    const float* __restrict__ Wv, const float* __restrict__ bv,
    float* __restrict__ qkv)   // [3][B,S,E]
{
    __shared__ float4 sx[64];
    const int bs = blockIdx.x;
    const int tid = threadIdx.x;
    if (tid < 64) sx[tid] = ((const float4*)(g + (size_t)bs * E_))[tid];
    __syncthreads();
    const int wid = tid >> 6, lane = tid & 63;
    const float4 x = sx[lane];
    for (int j = wid; j < 3 * E_; j += 4) {         // 768 row-dots
        const int m = j >> 8, r = j & 255;          // wave-uniform
        const float* W    = (m == 0 ? Wq : (m == 1 ? Wk : Wv));
        const float* bias = (m == 0 ? bq : (m == 1 ? bk : bv));
        float4 w = ((const float4*)(W + (size_t)r * E_))[lane];
        float sum = w.x * x.x + w.y * x.y + w.z * x.z + w.w * x.w;
        #pragma unroll
        for (int off = 32; off > 0; off >>= 1)
            sum += __shfl_down(sum, off, 64);
        if (lane == 0)
            qkv[(size_t)m * ROWS_ + (size_t)bs * E_ + r] = sum + bias[r];
    }
}

// ---------------- Kernel 2b: attention core ----------------
// one block (1 wave) per (b,h); 6x6 scores + softmax + PV in LDS
__global__ __launch_bounds__(64) void attn_core_kernel(
    const float* __restrict__ qkv, float* __restrict__ attended,
    float* __restrict__ attn_out)
{
    __shared__ float sq[S_ * HD_], sk[S_ * HD_], sv[S_ * HD_], sp[S_ * S_];
    const int b = blockIdx.x >> 3, h = blockIdx.x & 7;
    const int lane = threadIdx.x;
    const float* qb = qkv + (size_t)b * SE_ + h * HD_;
    const float* kb = qkv + (size_t)ROWS_ + (size_t)b * SE_ + h * HD_;
    const float* vb = qkv + (size_t)2 * ROWS_ + (size_t)b * SE_ + h * HD_;
    for (int idx = lane; idx < S_ * HD_; idx += 64) {
        int s = idx >> 5, d = idx & 31;
        sq[idx] = qb[s * E_ + d];
        sk[idx] = kb[s * E_ + d];
        sv[idx] = vb[s * E_ + d];
    }
    __syncthreads();
    const float inv_scale = 0.17677669529663687f;  // 1/sqrt(32)
    if (lane < S_ * S_) {
        int s = lane / S_, t = lane % S_;
        float sc = -INFINITY;
        if (t <= s) {
            sc = 0.f;
            #pragma unroll
            for (int d = 0; d < HD_; ++d)
                sc = fmaf(sq[s * HD_ + d], sk[t * HD_ + d], sc);
            sc *= inv_scale;
        }
        sp[lane] = sc;
    }
    __syncthreads();
    if (lane < S_) {
        const int s = lane;
        float m = -INFINITY;
        for (int t = 0; t <= s; ++t) m = fmaxf(m, sp[s * S_ + t]);
        float ex[S_], sum = 0.f;
        for (int t = 0; t <= s; ++t) { ex[t] = expf(sp[s * S_ + t] - m); sum += ex[t]; }
        float inv = 1.0f / sum;
        for (int t = 0; t < S_; ++t) sp[s * S_ + t] = (t <= s) ? ex[t] * inv : 0.0f;
    }
    __syncthreads();
    float* ab = attended + (size_t)b * SE_ + h * HD_;
    for (int idx = lane; idx < S_ * HD_; idx += 64) {
        int s = idx >> 5, d = idx & 31;
        float a = 0.f;
        for (int t = 0; t <= s; ++t)
            a = fmaf(sp[s * S_ + t], sv[t * HD_ + d], a);
        ab[s * E_ + d] = a;
    }
    if (lane < S_ * S_)
        attn_out[(size_t)b * (NH_ * S_ * S_) + h * (S_ * S_) + lane] = sp[lane];
}

// ---------------- Kernel 2c: output projection ----------------
__global__ __launch_bounds__(256) void oproj_kernel(
    const float* __restrict__ attended,
    const float* __restrict__ Wo, const float* __restrict__ bo,
    float* __restrict__ out_g)
{
    __shared__ float4 sx[64];
    const int bs = blockIdx.x;
    const int tid = threadIdx.x;
    if (tid < 64) sx[tid] = ((const float4*)(attended + (size_t)bs * E_))[tid];
    __syncthreads();
    const int wid = tid >> 6, lane = tid & 63;
    const float4 x = sx[lane];
    for (int r = wid; r < E_; r += 4) {
        float4 w = ((const float4*)(Wo + (size_t)r * E_))[lane];
        float sum = w.x * x.x + w.y * x.y + w.z * x.z + w.w * x.w;
        #pragma unroll
        for (int off = 32; off > 0; off >>= 1)
            sum += __shfl_down(sum, off, 64);
        if (lane == 0)
            out_g[(size_t)bs * E_ + r] = sum + bo[r];
    }
}

// ---------------- Kernel 3: broadcast add ----------------
__global__ __launch_bounds__(256) void add_kernel(
    const float* __restrict__ ff, const float* __restrict__ out_g,
    float* __restrict__ cross)
{
    const int row = blockIdx.x;
    const float add = out_g[row];      // wave-uniform -> scalar load
    const float4* p = (const float4*)(ff + (size_t)row * HW_);
    float4* q = (float4*)(cross + (size_t)row * HW_);
    #pragma unroll
    for (int i = 0; i < 4; ++i) {
        float4 v = p[threadIdx.x + i * 256];
        v.x += add; v.y += add; v.z += add; v.w += add;
        q[threadIdx.x + i * 256] = v;
    }
}

extern "C" void kernel_launch(void* const* d_in, const int* in_sizes, int n_in,
                              void* d_out, int out_size, void* d_ws, size_t ws_size,
                              hipStream_t stream) {
    const float* ff   = (const float*)d_in[0];
    const float* Wq   = (const float*)d_in[1];
    const float* bq   = (const float*)d_in[2];
    const float* Wk   = (const float*)d_in[3];
    const float* bk   = (const float*)d_in[4];
    const float* Wv   = (const float*)d_in[5];
    const float* bv   = (const float*)d_in[6];
    const float* Wo   = (const float*)d_in[7];
    const float* bo   = (const float*)d_in[8];
    const float* tpos = (const float*)d_in[9];

    float* out   = (float*)d_out;
    float* g        = (float*)d_ws;            // ROWS_ floats
    float* qkv      = g + ROWS_;               // 3*ROWS_ floats
    float* attended = qkv + 3 * ROWS_;         // ROWS_ floats
    float* out_g    = attended + ROWS_;        // ROWS_ floats

    float* cross    = out;                     // CROSS_N_ floats
    float* attn_out = out + CROSS_N_;          // 4608 floats

    pool_kernel<<<ROWS_, 256, 0, stream>>>(ff, tpos, g);
    qkv_kernel<<<BS_, 256, 0, stream>>>(g, Wq, bq, Wk, bk, Wv, bv, qkv);
    attn_core_kernel<<<B_ * NH_, 64, 0, stream>>>(qkv, attended, attn_out);
    oproj_kernel<<<BS_, 256, 0, stream>>>(attended, Wo, bo, out_g);
    add_kernel<<<ROWS_, 256, 0, stream>>>(ff, out_g, cross);
}